// Round 1
// baseline (132.733 us; speedup 1.0000x reference)
//
#include <hip/hip_runtime.h>
#include <math.h>

// Problem constants (fixed by setup_inputs)
#define NB 16
#define NT 50
#define NA 3
#define NG 76
#define NCELL (NG*NG)          // 5776
#define NCH 255                // 3*(5+80)
#define TOTCELLS (NB*NA*NCELL) // 277248
#define MAIN_BLOCKS ((TOTCELLS + 255) / 256) // 1083

static_assert(TOTCELLS == 277248, "geometry");

__device__ __forceinline__ float sigmoidf_(float v) { return 1.0f / (1.0f + expf(-v)); }

// ---------------------------------------------------------------------------
// Prep: per (b,t) target -> ignore map (shared across batches, per reference
// quirk) and winner map (last-write-wins over t, matching np scatter order).
// ---------------------------------------------------------------------------
__global__ void yolo_prep(const float* __restrict__ targets,
                          const float* __restrict__ anchors,
                          int* __restrict__ cell_zero,   // [NCELL], 0/1
                          int* __restrict__ winner)      // [TOTCELLS], t+1 or 0
{
    int idx = blockIdx.x * blockDim.x + threadIdx.x;
    if (idx >= NB * NT) return;
    int b = idx / NT, t = idx % NT;

    const float* T  = targets + (size_t)(b * NT + t) * 5;
    const float* T0 = targets + (size_t)(b * NT) * 5;
    float s = T[0] + T[1] + T[2] + T[3] + T[4];
    const float* U = (s > 0.0f) ? T : T0;   // rep(): invalid rows use t=0's row

    float gx = U[1] * (float)NG;
    float gy = U[2] * (float)NG;
    float gw = U[3] * (float)NG;
    float gh = U[4] * (float)NG;
    int gi = (int)gx, gj = (int)gy;

    float best_iou = -1e30f; int best = 0; bool ign = false;
#pragma unroll
    for (int a = 0; a < NA; ++a) {
        float aw = anchors[2 * a + 0] * 0.125f;   // anchors / stride, stride = 608/76 = 8
        float ah = anchors[2 * a + 1] * 0.125f;
        float inter = fmaxf(fminf(gw, aw) + 1.0f, 0.0f) *
                      fmaxf(fminf(gh, ah) + 1.0f, 0.0f);
        float denom = (gw + 1.0f) * (gh + 1.0f) + (aw + 1.0f) * (ah + 1.0f) - inter + 1e-12f;
        float iou = inter / denom;
        if (iou > 0.5f) ign = true;               // IGNORE_THRES
        if (iou > best_iou) { best_iou = iou; best = a; }  // first-max = argmax
    }

    if (ign) atomicOr(&cell_zero[gj * NG + gi], 1);
    atomicMax(&winner[((b * NA + best) * NG + gj) * NG + gi], t + 1);
}

// ---------------------------------------------------------------------------
// Main: one thread per (b,a,j,i) cell. Accumulate 8 sums:
// [0..3] masked MSE terms (x,y,w,h), [4] obj BCE, [5] noobj BCE,
// [6] n_mask, [7] n_noobj. Block partials in double -> ws.
// ---------------------------------------------------------------------------
__global__ __launch_bounds__(256) void yolo_main(
    const float* __restrict__ sample,
    const float* __restrict__ targets,
    const float* __restrict__ anchors,
    const int* __restrict__ cell_zero,
    const int* __restrict__ winner,
    double* __restrict__ partials)   // [MAIN_BLOCKS][8]
{
    double acc[8] = {0, 0, 0, 0, 0, 0, 0, 0};

    int idx = blockIdx.x * blockDim.x + threadIdx.x;
    if (idx < TOTCELLS) {
        int b    = idx / (NA * NCELL);
        int rem  = idx % (NA * NCELL);
        int a    = rem / NCELL;
        int cell = rem % NCELL;

        const float* S = sample + (size_t)(b * NCH + a * 85) * NCELL + cell;
        float px    = S[0 * NCELL];
        float py    = S[1 * NCELL];
        float pw    = S[2 * NCELL];
        float ph    = S[3 * NCELL];
        float pconf = S[4 * NCELL];
        float conf  = sigmoidf_(pconf);

        int w = winner[idx];
        if (w > 0) {
            // target cell: recompute the winning target's values (<=800 cells)
            int t = w - 1;
            const float* T  = targets + (size_t)(b * NT + t) * 5;
            const float* T0 = targets + (size_t)(b * NT) * 5;
            float s = T[0] + T[1] + T[2] + T[3] + T[4];
            const float* U = (s > 0.0f) ? T : T0;
            float gx = U[1] * (float)NG;
            float gy = U[2] * (float)NG;
            float gw = U[3] * (float)NG;
            float gh = U[4] * (float)NG;
            int gi = (int)gx, gj = (int)gy;
            float aw = anchors[2 * a + 0] * 0.125f;   // a == best_n for this cell
            float ah = anchors[2 * a + 1] * 0.125f;
            float tx = gx - (float)gi;
            float ty = gy - (float)gj;
            float tw = logf(gw / aw + 1e-16f);
            float th = logf(gh / ah + 1e-16f);
            float x = sigmoidf_(px), y = sigmoidf_(py);
            acc[0] += (double)((x - tx) * (x - tx));
            acc[1] += (double)((y - ty) * (y - ty));
            acc[2] += (double)((pw - tw) * (pw - tw));
            acc[3] += (double)((ph - th) * (ph - th));
            acc[4] += -(double)logf(conf + 1e-12f);          // obj BCE (t=1)
            acc[6] += 1.0;                                   // n_mask
        } else if (cell_zero[cell] == 0) {
            acc[5] += -(double)logf(1.0f - conf + 1e-12f);   // noobj BCE (t=0)
            acc[7] += 1.0;                                   // n_noobj
        }
    }

    // wave reduce (64 lanes), then cross-wave via LDS
#pragma unroll
    for (int k = 0; k < 8; ++k) {
        double v = acc[k];
#pragma unroll
        for (int o = 32; o > 0; o >>= 1) v += __shfl_down(v, o, 64);
        acc[k] = v;
    }
    __shared__ double sred[4][8];
    int lane = threadIdx.x & 63, wid = threadIdx.x >> 6;
    if (lane == 0) {
#pragma unroll
        for (int k = 0; k < 8; ++k) sred[wid][k] = acc[k];
    }
    __syncthreads();
    if (threadIdx.x < 8) {
        int k = threadIdx.x;
        partials[(size_t)blockIdx.x * 8 + k] =
            sred[0][k] + sred[1][k] + sred[2][k] + sred[3][k];
    }
}

// ---------------------------------------------------------------------------
// Finalize: reduce block partials, compute the 7 outputs.
// ---------------------------------------------------------------------------
__global__ __launch_bounds__(256) void yolo_final(const double* __restrict__ partials,
                                                  float* __restrict__ out)
{
    double acc[8] = {0, 0, 0, 0, 0, 0, 0, 0};
    for (int r = threadIdx.x; r < MAIN_BLOCKS; r += 256) {
#pragma unroll
        for (int k = 0; k < 8; ++k) acc[k] += partials[(size_t)r * 8 + k];
    }
#pragma unroll
    for (int k = 0; k < 8; ++k) {
        double v = acc[k];
#pragma unroll
        for (int o = 32; o > 0; o >>= 1) v += __shfl_down(v, o, 64);
        acc[k] = v;
    }
    __shared__ double sred[4][8];
    int lane = threadIdx.x & 63, wid = threadIdx.x >> 6;
    if (lane == 0) {
#pragma unroll
        for (int k = 0; k < 8; ++k) sred[wid][k] = acc[k];
    }
    __syncthreads();
    if (threadIdx.x == 0) {
        double red[8];
#pragma unroll
        for (int k = 0; k < 8; ++k)
            red[k] = sred[0][k] + sred[1][k] + sred[2][k] + sred[3][k];

        double nm = fmax(red[6], 1.0);   // max(sum(mask),1)
        double nn = fmax(red[7], 1.0);   // max(sum(cm_false),1)
        double lx = 2.0 * red[0] / nm;   // XY_LOSS
        double ly = 2.0 * red[1] / nm;
        double lw = 1.6 * red[2] / nm;   // WH_LOSS
        double lh = 1.6 * red[3] / nm;
        double lobj   = 1.0 * red[4] / nm;   // OBJ_LOSS
        double lnoobj = 0.5 * red[5] / nn;   // NOOBJ_LOSS

        out[0] = (float)(lx + ly + lw + lh + lnoobj + lobj);
        out[1] = (float)lx;
        out[2] = (float)ly;
        out[3] = (float)lw;
        out[4] = (float)lh;
        out[5] = (float)lobj;
        out[6] = (float)lnoobj;
    }
}

// ---------------------------------------------------------------------------
extern "C" void kernel_launch(void* const* d_in, const int* in_sizes, int n_in,
                              void* d_out, int out_size, void* d_ws, size_t ws_size,
                              hipStream_t stream)
{
    const float* sample  = (const float*)d_in[0];   // (16,255,76,76) f32
    const float* targets = (const float*)d_in[1];   // (16,50,5) f32
    const float* anchors = (const float*)d_in[2];   // (3,2) f32
    float* out = (float*)d_out;                     // 7 f32: loss + 6 comps

    char* ws = (char*)d_ws;
    int* cell_zero   = (int*)ws;                                    // 5776 ints
    int* winner      = (int*)(ws + (size_t)NCELL * sizeof(int));    // 277248 ints
    double* partials = (double*)(ws + (size_t)(NCELL + TOTCELLS) * sizeof(int)); // 1083*8 doubles

    // ws is re-poisoned 0xAA before every launch: zero the scatter maps.
    size_t zero_bytes = (size_t)(NCELL + TOTCELLS) * sizeof(int);
    hipMemsetAsync(d_ws, 0, zero_bytes, stream);

    yolo_prep<<<(NB * NT + 255) / 256, 256, 0, stream>>>(targets, anchors, cell_zero, winner);
    yolo_main<<<MAIN_BLOCKS, 256, 0, stream>>>(sample, targets, anchors, cell_zero, winner, partials);
    yolo_final<<<1, 256, 0, stream>>>(partials, out);
}